// Round 15
// baseline (59.641 us; speedup 1.0000x reference)
//
#include <hip/hip_runtime.h>
#include <math.h>

// DetectionLayer: x(32,255,76,76) f32 -> out(32,17328,85) f32
// R13 (NT-store, 59.4us) + corner finalization moved to an in-LDS fixup:
// phase B is now LOAD-FREE and near-branchless (R13 issued partner float4
// loads at use-time inside phase B -> exposed HBM latency for the waves
// owning the 120 clustered corner units; and a divergent 2-transcendental
// path). Partials for t<4 now land in LDS; 120 lanes finalize them there
// (reads/writes at stride 85 floats, 85%32=21 coprime -> conflict-free),
// at the cost of one extra lgkm-only barrier (loads long drained).
//
// Block (512 thr) = (b, row i, j-half). jh=0: cols [0,40), jh=1: cols [40,76).
// Phase A: batched float4 loads (NQ=10|9 vec4/channel, 16B-aligned).
// Phase B: transform in registers -> output-layout LDS lds[j*255+c].
//          t==2|3 -> __expf(x)*anc (half-extent partial); else sigm(x)
//          (final for t>=4, partial for t<2).
// Phase B2: corner fixup in LDS (JW*3 lanes, 4 slots each).
// Phase C: contiguous float4 NT dump (write-once stream, skip caches).
// LDS 40800B -> 4 blocks/CU x 8 waves = 32 waves/CU.
// XCD swizzle: logical (b,i,jh), jh fastest; 4864%8==0 -> bijective.

#define NCH    255
#define NATTR  85
#define HW     5776
#define GW     76
#define NBATCH 32
#define BLOCK  512
#define NWG    (NBATCH * GW * 2)   // 4864
#define CHUNK  (NWG / 8)           // 608

typedef float f32x4 __attribute__((ext_vector_type(4)));

__device__ __forceinline__ float sigm(float x) {
    return __builtin_amdgcn_rcpf(1.0f + __expf(-x));
}

template<int NQ>   // float4 units per channel: 10 (jh=0) or 9 (jh=1)
__device__ __forceinline__ void run_half(const float* __restrict__ src,
                                         float* __restrict__ dst,
                                         float* __restrict__ lds,
                                         int jg0, float fi) {
    constexpr int NU  = NCH * NQ;                  // 2550 / 2295 vec4 units
    constexpr int NIT = (NU + BLOCK - 1) / BLOCK;  // 5 / 5
    constexpr int JW  = 4 * NQ;                    // 40 / 36

    float4 xv[NIT];

    // ---- phase A: batched float4 loads ----
    #pragma unroll
    for (int k = 0; k < NIT; ++k) {
        int e = threadIdx.x + BLOCK * k;
        if (e < NU) {
            int c = e / NQ, q = e - c * NQ;
            xv[k] = *(const float4*)(src + (size_t)c * HW + 4 * q);
        }
    }

    // ---- phase B: load-free transform + output-layout LDS write ----
    #pragma unroll
    for (int k = 0; k < NIT; ++k) {
        int e = threadIdx.x + BLOCK * k;
        if (e < NU) {
            int c = e / NQ, q = e - c * NQ;
            int a = c / 85;              // exact (compiler magic-mul)
            int t = c - 85 * a;
            float4 v = xv[k];
            float r0, r1, r2, r3;
            if ((t | 1) == 3) {          // t==2 || t==3: half-extent partial
                float anc = ((t == 2)
                    ? ((a == 0) ? 10.f : (a == 1) ? 16.f : 33.f)
                    : ((a == 0) ? 13.f : (a == 1) ? 30.f : 23.f)) * (0.5f / 608.f);
                r0 = __expf(v.x) * anc; r1 = __expf(v.y) * anc;
                r2 = __expf(v.z) * anc; r3 = __expf(v.w) * anc;
            } else {                     // sigm: final t>=4, partial t<2
                r0 = sigm(v.x); r1 = sigm(v.y); r2 = sigm(v.z); r3 = sigm(v.w);
            }
            float* lp = &lds[(4 * q) * NCH + c];
            lp[0]       = r0;
            lp[NCH]     = r1;
            lp[2 * NCH] = r2;
            lp[3 * NCH] = r3;
        }
    }
    __syncthreads();

    // ---- phase B2: corner fixup in LDS (JW cols x 3 anchors) ----
    if (threadIdx.x < JW * 3) {
        int j = threadIdx.x / 3;
        int a = threadIdx.x - 3 * j;
        float* p = &lds[j * NCH + a * NATTR];
        float s0 = p[0], s1 = p[1], w2 = p[2], h2 = p[3];
        float ix = (s0 * 1.05f - 0.025f + (float)(jg0 + j)) * (1.0f / 76.0f);
        float iy = (s1 * 1.05f - 0.025f + fi) * (1.0f / 76.0f);
        p[0] = ix - w2; p[1] = iy - h2; p[2] = ix + w2; p[3] = iy + h2;
    }
    __syncthreads();

    // ---- phase C: contiguous float4 NON-TEMPORAL dump ----
    f32x4* __restrict__ dv = (f32x4*)dst;
    const f32x4* lv = (const f32x4*)lds;
    #pragma unroll
    for (int k = 0; k < NIT; ++k) {
        int e = threadIdx.x + BLOCK * k;
        if (e < NU) __builtin_nontemporal_store(lv[e], &dv[e]);
    }
}

__global__ __launch_bounds__(BLOCK, 8) void det_kernel(const float* __restrict__ in,
                                                       float* __restrict__ out) {
    __shared__ float lds[NCH * 40];    // 40800 B -> 4 blocks/CU

    int hw = blockIdx.x;
    int L  = (hw & 7) * CHUNK + (hw >> 3);
    int jh = L & 1;
    int L2 = L >> 1;
    int i  = L2 % GW;
    int b  = L2 / GW;

    const float* __restrict__ src = in + (size_t)b * (NCH * HW) + (size_t)i * GW;
    float* __restrict__ dst = out + ((size_t)b * 17328 + (size_t)i * 228) * NATTR;
    const float fi = (float)i;

    if (jh == 0) {
        run_half<10>(src, dst, lds, 0, fi);
    } else {
        run_half<9>(src + 40, dst + 40 * NCH, lds, 40, fi);
    }
}

extern "C" void kernel_launch(void* const* d_in, const int* in_sizes, int n_in,
                              void* d_out, int out_size, void* d_ws, size_t ws_size,
                              hipStream_t stream) {
    const float* x = (const float*)d_in[0];
    float* out = (float*)d_out;
    det_kernel<<<NWG, BLOCK, 0, stream>>>(x, out);
}